// Round 1
// baseline (379.761 us; speedup 1.0000x reference)
//
#include <hip/hip_runtime.h>

// LocalGLMnet fused forward: interim = sigmoid(locally-connected 5x5), then
// forecast = sum_i x*interim, penalty = 0.01*sum_i interim^2.
// B=16384, H=10, W=100, kernel 5x5, pad 2. Output (B, 2, 100) f32.
//
// Mapping: thread = (j, group of NB=4 batches). Lanes span consecutive j ->
// coalesced x loads / out stores. Block owns one j-half (50 j's): its weight
// tile (10*50*25 f32 = 50 KB) is staged to LDS ONCE (3 blocks/CU).
// Per thread: rolling 5x5 register window per batch; each x element is loaded
// exactly once per thread; weights read from LDS once per i, reused 4x.

#define L2E 1.44269504088896340736f

__device__ __forceinline__ float fast_sigmoid(float s) {
    float e = __builtin_amdgcn_exp2f(s * (-L2E));   // exp(-s)
    return __builtin_amdgcn_rcpf(1.0f + e);         // 1/(1+exp(-s))
}

__global__ __launch_bounds__(256, 3)
void glm_fused(const float* __restrict__ x, const float* __restrict__ w,
               float* __restrict__ out) {
    __shared__ float wl[12500];  // [i][jl*25+dd], jl in [0,50) for this j-half

    const int tid = threadIdx.x;
    const int jh  = blockIdx.x & 1;   // which j-half: 0 -> j 0..49, 1 -> j 50..99
    const int blk = blockIdx.x >> 1;  // 0..799

    // ---- stage weight half-tile once: w[i*2500 + jh*1250 + r] -> wl[i*1250 + r]
    {
        const float2* __restrict__ src = (const float2*)w;
        float2* dst = (float2*)wl;
        for (int u = tid; u < 6250; u += 256) {   // 6250 float2 = 12500 floats
            int i  = u / 625;
            int r2 = u - i * 625;
            dst[i * 625 + r2] = src[i * 1250 + jh * 625 + r2];
        }
    }
    __syncthreads();

    const int tl = blk * 256 + tid;   // 0..204799
    const int jl = tl % 50;
    const int bg = tl / 50;           // 0..4095 (group of 4 batches)
    const int j  = jh * 50 + jl;

    const float* __restrict__ xb = x + bg * 4000;  // 4 batches x (10*100)

    // window cols c=0..4 -> global col j-2+c ; mask out-of-range (zero pad)
    int  ccol[5];
    bool cval[5];
#pragma unroll
    for (int c = 0; c < 5; ++c) {
        int col = j - 2 + c;
        cval[c] = (unsigned)col < 100u;
        ccol[c] = cval[c] ? col : 0;
    }

    float win[4][5][5];   // [batch][row slot][col]; slot = (x_row mod 5)
    float fore[4] = {0.f, 0.f, 0.f, 0.f};
    float pen[4]  = {0.f, 0.f, 0.f, 0.f};

    // rows -2,-1 (slots 3,4) are zero padding
#pragma unroll
    for (int k = 0; k < 4; ++k)
#pragma unroll
        for (int c = 0; c < 5; ++c) { win[k][3][c] = 0.f; win[k][4][c] = 0.f; }

    // preload x rows 0,1 -> slots 0,1
#pragma unroll
    for (int r = 0; r < 2; ++r)
#pragma unroll
        for (int k = 0; k < 4; ++k)
#pragma unroll
            for (int c = 0; c < 5; ++c) {
                float v = xb[k * 1000 + r * 100 + ccol[c]];
                win[k][r][c] = cval[c] ? v : 0.f;
            }

#pragma unroll
    for (int i = 0; i < 10; ++i) {
        // load x row i+2 into slot (i+2)%5 (zeros beyond row 9)
        const int rin = i + 2;
        const int sl  = rin % 5;
        if (rin <= 9) {
#pragma unroll
            for (int k = 0; k < 4; ++k)
#pragma unroll
                for (int c = 0; c < 5; ++c) {
                    float v = xb[k * 1000 + rin * 100 + ccol[c]];
                    win[k][sl][c] = cval[c] ? v : 0.f;
                }
        } else {
#pragma unroll
            for (int k = 0; k < 4; ++k)
#pragma unroll
                for (int c = 0; c < 5; ++c) win[k][sl][c] = 0.f;
        }

        // weights for (i, j): 25 consecutive floats in LDS, reused by 4 batches
        const float* wrow = &wl[i * 1250 + jl * 25];
        float wf[25];
#pragma unroll
        for (int d = 0; d < 25; ++d) wf[d] = wrow[d];

#pragma unroll
        for (int k = 0; k < 4; ++k) {
            float s = 0.f;
#pragma unroll
            for (int di = 0; di < 5; ++di) {
                const int slot = (i + di + 3) % 5;  // x row i-2+di
#pragma unroll
                for (int c = 0; c < 5; ++c)
                    s = fmaf(win[k][slot][c], wf[di * 5 + c], s);
            }
            float itm = fast_sigmoid(s);
            fore[k] = fmaf(win[k][i % 5][2], itm, fore[k]);  // x[b,i,j]*interim
            pen[k]  = fmaf(0.01f * itm, itm, pen[k]);        // 0.01*interim^2
        }
    }

    // out[b][ch][j], b = bg*4+k: base = bg*800 + k*200 + ch*100 + j
    float* ob = out + bg * 800 + j;
#pragma unroll
    for (int k = 0; k < 4; ++k) {
        ob[k * 200]       = fore[k];
        ob[k * 200 + 100] = pen[k];
    }
}

extern "C" void kernel_launch(void* const* d_in, const int* in_sizes, int n_in,
                              void* d_out, int out_size, void* d_ws, size_t ws_size,
                              hipStream_t stream) {
    const float* x = (const float*)d_in[0];   // (16384, 10, 100) f32
    const float* w = (const float*)d_in[1];   // (10, 100, 5, 5)  f32
    float* out = (float*)d_out;               // (16384, 2, 100)  f32
    dim3 grid(1600), block(256);
    hipLaunchKernelGGL(glm_fused, grid, block, 0, stream, x, w, out);
}